// Round 7
// baseline (117.634 us; speedup 1.0000x reference)
//
#include <hip/hip_runtime.h>
#include <math.h>

#define OUT_F      4096
#define IN_F       4096
#define NUM_CHUNKS 16384
#define CHUNK_SIZE 1024
#define D_ALPHA    64
#define HIDDEN     256
#define TOKENS     256

typedef __attribute__((ext_vector_type(8))) __bf16 bf16x8;
typedef __attribute__((ext_vector_type(4))) __bf16 bf16x4;
typedef __attribute__((ext_vector_type(4))) float f32x4;

__device__ __forceinline__ void gl2lds16(const void* g, void* l) {
    __builtin_amdgcn_global_load_lds(
        (const __attribute__((address_space(1))) void*)g,
        (__attribute__((address_space(3))) void*)l,
        16, 0, 0);
}

// ============ K1: fused prep + Y-GEMM =======================================
// blocks [0,64)      : Y = xr(1024x1024) @ w2^T-on-the-fly  (MFMA, 64x64,BK=128)
// blocks [64,1088)   : H = gelu(codebook @ w1^T + b1) via MFMA, 64x64 tile
// blocks [1088,1344) : xb2[t] = dot(x[t], tile(b2))
__global__ __launch_bounds__(256) void fused_prep(
    const float* __restrict__ cb, const float* __restrict__ w1,
    const float* __restrict__ b1, const float* __restrict__ x,
    const float* __restrict__ b2, const float* __restrict__ w2,
    __bf16* __restrict__ H, __bf16* __restrict__ Y,
    float* __restrict__ xb2) {
    __shared__ __align__(16) char smem[33792];   // sA 16K + sB 64*136*2
    const int b   = blockIdx.x;
    const int tid = threadIdx.x;

    if (b < 64) {
        // ---- Y-GEMM: M=1024 (xr rows), N=256 (hidden), K=1024 (p) ----
        // A = x fp32 flat (1024x1024), converted to bf16 in staging.
        // B = w2[p][h] fp32, transposed+converted into LDS (stride 136, padded).
        constexpr int BK = 128, SBS = 136;
        const int mt = b & 15, nt = b >> 4;      // 16 m-tiles x 4 n-tiles
        const int m0 = mt * 64, h0 = nt * 64;
        __bf16* sA = (__bf16*)smem;              // 64 x 128
        __bf16* sB = (__bf16*)(smem + 16384);    // 64 x 136 (padded stride)

        const int wave = tid >> 6, lane = tid & 63;
        const int wm = (wave & 1) * 32, wn = (wave >> 1) * 32;
        const int fr = lane & 15, fq = lane >> 4;
        f32x4 acc[2][2] = {};

        for (int k0 = 0; k0 < 1024; k0 += BK) {
            // stage A: 64 rows x 128 k, fp32 -> bf16
#pragma unroll
            for (int c = 0; c < 8; ++c) {
                const int idx = c * 256 + tid;
                const int row = idx >> 5, k4 = idx & 31;
                float4 v = *reinterpret_cast<const float4*>(
                    x + (size_t)(m0 + row) * 1024 + k0 + k4 * 4);
                bf16x4 o;
                o.x = (__bf16)v.x; o.y = (__bf16)v.y;
                o.z = (__bf16)v.z; o.w = (__bf16)v.w;
                *reinterpret_cast<bf16x4*>(sA + row * BK + k4 * 4) = o;
            }
            // stage B: w2 slab (128p x 64h) -> sB[h][p] bf16, 4x4 transpose
#pragma unroll
            for (int c = 0; c < 2; ++c) {
                const int idx = c * 256 + tid;
                const int h4 = idx & 15, pq = idx >> 4;
                float4 vv[4];
#pragma unroll
                for (int dp = 0; dp < 4; ++dp)
                    vv[dp] = *reinterpret_cast<const float4*>(
                        w2 + (size_t)(k0 + pq * 4 + dp) * HIDDEN + h0 + h4 * 4);
#pragma unroll
                for (int dh = 0; dh < 4; ++dh) {
                    bf16x4 o;
                    o.x = (__bf16)((const float*)&vv[0])[dh];
                    o.y = (__bf16)((const float*)&vv[1])[dh];
                    o.z = (__bf16)((const float*)&vv[2])[dh];
                    o.w = (__bf16)((const float*)&vv[3])[dh];
                    *reinterpret_cast<bf16x4*>(
                        sB + (h4 * 4 + dh) * SBS + pq * 4) = o;
                }
            }
            __syncthreads();
#pragma unroll
            for (int u = 0; u < BK / 32; ++u) {
                bf16x8 af[2], bv[2];
#pragma unroll
                for (int i = 0; i < 2; ++i) {
                    af[i] = *reinterpret_cast<const bf16x8*>(
                        sA + (wm + i * 16 + fr) * BK + u * 32 + fq * 8);
                    bv[i] = *reinterpret_cast<const bf16x8*>(
                        sB + (wn + i * 16 + fr) * SBS + u * 32 + fq * 8);
                }
#pragma unroll
                for (int i = 0; i < 2; ++i)
#pragma unroll
                    for (int j = 0; j < 2; ++j)
                        acc[i][j] = __builtin_amdgcn_mfma_f32_16x16x32_bf16(
                            af[i], bv[j], acc[i][j], 0, 0, 0);
            }
            __syncthreads();
        }
#pragma unroll
        for (int j = 0; j < 2; ++j) {
            const int col = h0 + wn + j * 16 + fr;
#pragma unroll
            for (int i = 0; i < 2; ++i) {
                const int rbase = m0 + wm + i * 16 + fq * 4;
#pragma unroll
                for (int r = 0; r < 4; ++r)
                    Y[(size_t)(rbase + r) * HIDDEN + col] = (__bf16)acc[i][j][r];
            }
        }
    } else if (b < 1088) {
        // ---- hidden via MFMA: tile (by: 64 chunks) x (bx: 64 hidden), K=64
        const int bb = b - 64;
        const int by = bb >> 2, bx = bb & 3;
        const int c0 = by * 64, h0 = bx * 64;
        __bf16* sA = (__bf16*)smem;
        __bf16* sB = (__bf16*)(smem + 8192);
        const float4* cb4 = reinterpret_cast<const float4*>(cb) + (size_t)by * 1024;
        const float4* w14 = reinterpret_cast<const float4*>(w1) + (size_t)bx * 1024;
#pragma unroll
        for (int q = 0; q < 4; ++q) {
            const int idx = q * 256 + tid;
            float4 va = cb4[idx];
            float4 vb = w14[idx];
            bf16x4 oa, ob;
            oa.x = (__bf16)va.x; oa.y = (__bf16)va.y; oa.z = (__bf16)va.z; oa.w = (__bf16)va.w;
            ob.x = (__bf16)vb.x; ob.y = (__bf16)vb.y; ob.z = (__bf16)vb.z; ob.w = (__bf16)vb.w;
            *reinterpret_cast<bf16x4*>(sA + idx * 4) = oa;
            *reinterpret_cast<bf16x4*>(sB + idx * 4) = ob;
        }
        __syncthreads();
        const int wave = tid >> 6, lane = tid & 63;
        const int wm = (wave & 1) * 32, wn = (wave >> 1) * 32;
        const int fr = lane & 15, fq = lane >> 4;
        f32x4 acc[2][2] = {};
        bf16x8 af[2][2], bv[2][2];
#pragma unroll
        for (int i = 0; i < 2; ++i)
#pragma unroll
            for (int u = 0; u < 2; ++u) {
                af[i][u] = *reinterpret_cast<const bf16x8*>(
                    sA + (wm + i * 16 + fr) * 64 + u * 32 + fq * 8);
                bv[i][u] = *reinterpret_cast<const bf16x8*>(
                    sB + (wn + i * 16 + fr) * 64 + u * 32 + fq * 8);
            }
#pragma unroll
        for (int u = 0; u < 2; ++u)
#pragma unroll
            for (int i = 0; i < 2; ++i)
#pragma unroll
                for (int j = 0; j < 2; ++j)
                    acc[i][j] = __builtin_amdgcn_mfma_f32_16x16x32_bf16(
                        af[i][u], bv[j][u], acc[i][j], 0, 0, 0);
#pragma unroll
        for (int j = 0; j < 2; ++j) {
            const int col = h0 + wn + j * 16 + fr;
            const float bb1 = b1[col];
#pragma unroll
            for (int i = 0; i < 2; ++i) {
                const int rbase = c0 + wm + i * 16 + fq * 4;
#pragma unroll
                for (int r = 0; r < 4; ++r) {
                    float v = acc[i][j][r] + bb1;
                    float g = 0.5f * v * (1.0f + erff(v * 0.70710678118654752f));
                    H[(size_t)(rbase + r) * 256 + col] = (__bf16)g;
                }
            }
        }
    } else {
        // ---- xb2[t] = dot(x[t], tiled b2) ----
        float* ws_ = (float*)smem;
        const int t = b - 1088;
        const float4* xr  = reinterpret_cast<const float4*>(x + (size_t)t * IN_F);
        const float4* b24 = reinterpret_cast<const float4*>(b2);
        float acc = 0.0f;
#pragma unroll
        for (int ii = 0; ii < 4; ++ii) {
            const int idx = ii * 256 + tid;
            float4 v = xr[idx];
            float4 bb = b24[idx & 255];
            acc += v.x * bb.x + v.y * bb.y + v.z * bb.z + v.w * bb.w;
        }
#pragma unroll
        for (int off = 32; off > 0; off >>= 1) acc += __shfl_down(acc, off, 64);
        if ((tid & 63) == 0) ws_[tid >> 6] = acc;
        __syncthreads();
        if (tid == 0) xb2[t] = ws_[0] + ws_[1] + ws_[2] + ws_[3];
    }
}

// ============ K2: out-GEMM, 64x64 tile, BK=128 ==============================
// out = Ycat(256x1024) @ Hflat(4096x1024)^T + bias[col] + xb2[row]
__global__ __launch_bounds__(256) void gemm_out(
    const __bf16* __restrict__ A, const __bf16* __restrict__ B,
    const float* __restrict__ bias, const float* __restrict__ rowterm,
    float* __restrict__ C, int M, int N, int K) {
    constexpr int BK = 128;
    __shared__ __bf16 sA[64 * BK];
    __shared__ __bf16 sB[64 * BK];
    const int tid = threadIdx.x;
    const int m0 = blockIdx.y * 64;
    const int n0 = blockIdx.x * 64;

    constexpr int NC = BK / 32;
    int rowc[NC], colc[NC];
#pragma unroll
    for (int c = 0; c < NC; ++c) {
        const int flat = c * 2048 + tid * 8;
        rowc[c] = flat / BK;
        colc[c] = flat % BK;
    }

    const int wave = tid >> 6, lane = tid & 63;
    const int wm = (wave & 1) * 32, wn = (wave >> 1) * 32;
    const int fr = lane & 15, fq = lane >> 4;

    f32x4 acc[2][2] = {};

    for (int k0 = 0; k0 < K; k0 += BK) {
#pragma unroll
        for (int c = 0; c < NC; ++c) {
            gl2lds16(A + (size_t)(m0 + rowc[c]) * K + k0 + colc[c],
                     sA + c * 2048 + tid * 8);
            gl2lds16(B + (size_t)(n0 + rowc[c]) * K + k0 + colc[c],
                     sB + c * 2048 + tid * 8);
        }
        __syncthreads();

#pragma unroll
        for (int u = 0; u < BK / 32; ++u) {
            bf16x8 af[2], bv[2];
#pragma unroll
            for (int i = 0; i < 2; ++i) {
                af[i] = *reinterpret_cast<const bf16x8*>(
                    sA + (wm + i * 16 + fr) * BK + u * 32 + fq * 8);
                bv[i] = *reinterpret_cast<const bf16x8*>(
                    sB + (wn + i * 16 + fr) * BK + u * 32 + fq * 8);
            }
#pragma unroll
            for (int i = 0; i < 2; ++i)
#pragma unroll
                for (int j = 0; j < 2; ++j)
                    acc[i][j] = __builtin_amdgcn_mfma_f32_16x16x32_bf16(
                        af[i], bv[j], acc[i][j], 0, 0, 0);
        }
        __syncthreads();
    }

#pragma unroll
    for (int j = 0; j < 2; ++j) {
        const int col = n0 + wn + j * 16 + fr;
        const float bvs = bias[col];
#pragma unroll
        for (int i = 0; i < 2; ++i) {
            const int rbase = m0 + wm + i * 16 + fq * 4;
#pragma unroll
            for (int r = 0; r < 4; ++r)
                C[(size_t)(rbase + r) * N + col] =
                    acc[i][j][r] + bvs + rowterm[rbase + r];
        }
    }
}

extern "C" void kernel_launch(void* const* d_in, const int* in_sizes, int n_in,
                              void* d_out, int out_size, void* d_ws, size_t ws_size,
                              hipStream_t stream) {
    const float* x        = (const float*)d_in[0];
    const float* codebook = (const float*)d_in[1];
    const float* w1       = (const float*)d_in[2];
    const float* b1       = (const float*)d_in[3];
    const float* w2       = (const float*)d_in[4];
    const float* b2       = (const float*)d_in[5];
    const float* bias     = (const float*)d_in[6];
    float* out = (float*)d_out;

    // ws layout (MB offsets):
    //   H    bf16 16384x256  8 MB @ 0
    //   Y    bf16 1024x256  .5 MB @ 8
    //   xb2  fp32 256        1 KB @ 9
    char* ws = (char*)d_ws;
    __bf16* H   = (__bf16*)(ws);
    __bf16* Y   = (__bf16*)(ws + (8u << 20));
    float*  xb2 = (float*)(ws + (9u << 20));

    // K1: Y-GEMM (64 blocks, first) + hidden-MFMA (1024) + xb2 rowdots (256)
    fused_prep<<<1344, 256, 0, stream>>>(codebook, w1, b1, x, b2, w2,
                                         H, Y, xb2);

    // K2: out = Ycat(256x1024) @ Hflat^T + bias[col] + xb2[row]
    {
        dim3 grid(OUT_F / 64, TOKENS / 64, 1);   // 64 x 4 = 256 blocks
        gemm_out<<<grid, 256, 0, stream>>>(
            Y, H, bias, xb2, out, TOKENS, OUT_F, 1024);
    }
}

// Round 8
// 105.520 us; speedup vs baseline: 1.1148x; 1.1148x over previous
//
#include <hip/hip_runtime.h>
#include <math.h>

#define OUT_F      4096
#define IN_F       4096
#define NUM_CHUNKS 16384
#define CHUNK_SIZE 1024
#define D_ALPHA    64
#define HIDDEN     256
#define TOKENS     256

typedef __attribute__((ext_vector_type(8))) __bf16 bf16x8;
typedef __attribute__((ext_vector_type(4))) __bf16 bf16x4;
typedef __attribute__((ext_vector_type(4))) float f32x4;

__device__ __forceinline__ void gl2lds16(const void* g, void* l) {
    __builtin_amdgcn_global_load_lds(
        (const __attribute__((address_space(1))) void*)g,
        (__attribute__((address_space(3))) void*)l,
        16, 0, 0);
}

// ============ K1: fused prep ================================================
// blocks [0,1024)     : H = gelu(codebook @ w1^T + b1) via MFMA, 64x64 tile
// blocks [1024,1280)  : x fp32->bf16 + xb2[t] = dot(x[t], tile(b2))
// blocks [1280,1536)  : w2 (1024x256) -> w2t bf16 (256x1024)
__global__ __launch_bounds__(256) void prep_kernel(
    const float* __restrict__ cb, const float* __restrict__ w1,
    const float* __restrict__ b1, const float* __restrict__ x,
    const float* __restrict__ b2, const float* __restrict__ w2,
    __bf16* __restrict__ H, __bf16* __restrict__ xb,
    float* __restrict__ xb2, __bf16* __restrict__ w2t) {
    __shared__ char smem[16384];
    const int b   = blockIdx.x;
    const int tid = threadIdx.x;

    if (b < 1024) {
        // ---- hidden via MFMA: tile (by: 64 chunks) x (bx: 64 hidden), K=64
        const int by = b >> 2;
        const int bx = b & 3;
        const int c0 = by * 64, h0 = bx * 64;
        __bf16* sA = (__bf16*)smem;            // 64x64 bf16 (8 KB)
        __bf16* sB = (__bf16*)(smem + 8192);   // 64x64 bf16
        const float4* cb4 = reinterpret_cast<const float4*>(cb) + (size_t)by * 1024;
        const float4* w14 = reinterpret_cast<const float4*>(w1) + (size_t)bx * 1024;
#pragma unroll
        for (int q = 0; q < 4; ++q) {
            const int idx = q * 256 + tid;
            float4 va = cb4[idx];
            float4 vb = w14[idx];
            bf16x4 oa, ob;
            oa.x = (__bf16)va.x; oa.y = (__bf16)va.y; oa.z = (__bf16)va.z; oa.w = (__bf16)va.w;
            ob.x = (__bf16)vb.x; ob.y = (__bf16)vb.y; ob.z = (__bf16)vb.z; ob.w = (__bf16)vb.w;
            *reinterpret_cast<bf16x4*>(sA + idx * 4) = oa;
            *reinterpret_cast<bf16x4*>(sB + idx * 4) = ob;
        }
        __syncthreads();
        const int wave = tid >> 6, lane = tid & 63;
        const int wm = (wave & 1) * 32, wn = (wave >> 1) * 32;
        const int fr = lane & 15, fq = lane >> 4;
        f32x4 acc[2][2] = {};
        bf16x8 af[2][2], bv[2][2];
#pragma unroll
        for (int i = 0; i < 2; ++i)
#pragma unroll
            for (int u = 0; u < 2; ++u) {
                af[i][u] = *reinterpret_cast<const bf16x8*>(
                    sA + (wm + i * 16 + fr) * 64 + u * 32 + fq * 8);
                bv[i][u] = *reinterpret_cast<const bf16x8*>(
                    sB + (wn + i * 16 + fr) * 64 + u * 32 + fq * 8);
            }
#pragma unroll
        for (int u = 0; u < 2; ++u)
#pragma unroll
            for (int i = 0; i < 2; ++i)
#pragma unroll
                for (int j = 0; j < 2; ++j)
                    acc[i][j] = __builtin_amdgcn_mfma_f32_16x16x32_bf16(
                        af[i][u], bv[j][u], acc[i][j], 0, 0, 0);
#pragma unroll
        for (int j = 0; j < 2; ++j) {
            const int col = h0 + wn + j * 16 + fr;
            const float bb = b1[col];
#pragma unroll
            for (int i = 0; i < 2; ++i) {
                const int rbase = c0 + wm + i * 16 + fq * 4;
#pragma unroll
                for (int r = 0; r < 4; ++r) {
                    float v = acc[i][j][r] + bb;
                    float g = 0.5f * v * (1.0f + erff(v * 0.70710678118654752f));
                    H[(size_t)(rbase + r) * 256 + col] = (__bf16)g;
                }
            }
        }
    } else if (b < 1280) {
        // ---- x convert + row dot with tiled b2 ----
        float* ws_ = (float*)smem;
        const int t = b - 1024;
        const float4* xr  = reinterpret_cast<const float4*>(x + (size_t)t * IN_F);
        const float4* b24 = reinterpret_cast<const float4*>(b2);
        bf16x4* xb4 = reinterpret_cast<bf16x4*>(xb + (size_t)t * IN_F);
        float acc = 0.0f;
#pragma unroll
        for (int ii = 0; ii < 4; ++ii) {
            const int idx = ii * 256 + tid;
            float4 v = xr[idx];
            bf16x4 o;
            o.x = (__bf16)v.x; o.y = (__bf16)v.y; o.z = (__bf16)v.z; o.w = (__bf16)v.w;
            xb4[idx] = o;
            float4 bb = b24[idx & 255];
            acc += v.x * bb.x + v.y * bb.y + v.z * bb.z + v.w * bb.w;
        }
#pragma unroll
        for (int off = 32; off > 0; off >>= 1) acc += __shfl_down(acc, off, 64);
        if ((tid & 63) == 0) ws_[tid >> 6] = acc;
        __syncthreads();
        if (tid == 0) xb2[t] = ws_[0] + ws_[1] + ws_[2] + ws_[3];
    } else {
        // ---- w2 transpose -> bf16 ----
        float (*tile)[33] = (float (*)[33])smem;
        const int bb = b - 1280;
        const int h0 = (bb & 7) * 32;          // HIDDEN/32 = 8
        const int p0 = (bb >> 3) * 32;
        const int r = tid >> 5;
        const int c = tid & 31;
#pragma unroll
        for (int ii = 0; ii < 4; ++ii)
            tile[r + 8 * ii][c] = w2[(size_t)(p0 + r + 8 * ii) * HIDDEN + h0 + c];
        __syncthreads();
#pragma unroll
        for (int ii = 0; ii < 4; ++ii)
            w2t[(size_t)(h0 + r + 8 * ii) * CHUNK_SIZE + p0 + c] =
                (__bf16)tile[c][r + 8 * ii];
    }
}

// ============ bf16 MFMA GEMM, 64x64 tile, templated BK ======================
// C = A[M][K] @ B[N][K]^T ; 256 thr = 4 waves (2x2), wave 32x32 = 2x2 mfma.
// EPI 0: bf16 out, no bias.   EPI 1: fp32 out += bias[col] + rowterm[row].
template <int BK, int EPI>
__global__ __launch_bounds__(256) void gemm_bt64(
    const __bf16* __restrict__ A, const __bf16* __restrict__ B,
    const float* __restrict__ bias, const float* __restrict__ rowterm,
    void* __restrict__ Cv, int M, int N, int K) {
    __shared__ __bf16 sA[64 * BK];
    __shared__ __bf16 sB[64 * BK];
    const int tid = threadIdx.x;
    const int m0 = blockIdx.y * 64;
    const int n0 = blockIdx.x * 64;

    constexpr int NC = BK / 32;     // 16B staging chunks per thread per matrix
    int rowc[NC], colc[NC];
#pragma unroll
    for (int c = 0; c < NC; ++c) {
        const int flat = c * 2048 + tid * 8;
        rowc[c] = flat / BK;
        colc[c] = flat % BK;
    }

    const int wave = tid >> 6, lane = tid & 63;
    const int wm = (wave & 1) * 32, wn = (wave >> 1) * 32;
    const int fr = lane & 15, fq = lane >> 4;

    f32x4 acc[2][2] = {};

    for (int k0 = 0; k0 < K; k0 += BK) {
#pragma unroll
        for (int c = 0; c < NC; ++c) {
            gl2lds16(A + (size_t)(m0 + rowc[c]) * K + k0 + colc[c],
                     sA + c * 2048 + tid * 8);
            gl2lds16(B + (size_t)(n0 + rowc[c]) * K + k0 + colc[c],
                     sB + c * 2048 + tid * 8);
        }
        __syncthreads();

#pragma unroll
        for (int u = 0; u < BK / 32; ++u) {
            bf16x8 af[2], bv[2];
#pragma unroll
            for (int i = 0; i < 2; ++i) {
                af[i] = *reinterpret_cast<const bf16x8*>(
                    sA + (wm + i * 16 + fr) * BK + u * 32 + fq * 8);
                bv[i] = *reinterpret_cast<const bf16x8*>(
                    sB + (wn + i * 16 + fr) * BK + u * 32 + fq * 8);
            }
#pragma unroll
            for (int i = 0; i < 2; ++i)
#pragma unroll
                for (int j = 0; j < 2; ++j)
                    acc[i][j] = __builtin_amdgcn_mfma_f32_16x16x32_bf16(
                        af[i], bv[j], acc[i][j], 0, 0, 0);
        }
        __syncthreads();
    }

    if (EPI == 0) {
        __bf16* C = (__bf16*)Cv;
#pragma unroll
        for (int j = 0; j < 2; ++j) {
            const int col = n0 + wn + j * 16 + fr;
#pragma unroll
            for (int i = 0; i < 2; ++i) {
                const int rbase = m0 + wm + i * 16 + fq * 4;
#pragma unroll
                for (int r = 0; r < 4; ++r)
                    C[(size_t)(rbase + r) * N + col] = (__bf16)acc[i][j][r];
            }
        }
    } else {
        float* C = (float*)Cv;
#pragma unroll
        for (int j = 0; j < 2; ++j) {
            const int col = n0 + wn + j * 16 + fr;
            const float bvs = bias[col];
#pragma unroll
            for (int i = 0; i < 2; ++i) {
                const int rbase = m0 + wm + i * 16 + fq * 4;
#pragma unroll
                for (int r = 0; r < 4; ++r)
                    C[(size_t)(rbase + r) * N + col] =
                        acc[i][j][r] + bvs + rowterm[rbase + r];
            }
        }
    }
}

extern "C" void kernel_launch(void* const* d_in, const int* in_sizes, int n_in,
                              void* d_out, int out_size, void* d_ws, size_t ws_size,
                              hipStream_t stream) {
    const float* x        = (const float*)d_in[0];
    const float* codebook = (const float*)d_in[1];
    const float* w1       = (const float*)d_in[2];
    const float* b1       = (const float*)d_in[3];
    const float* w2       = (const float*)d_in[4];
    const float* b2       = (const float*)d_in[5];
    const float* bias     = (const float*)d_in[6];
    float* out = (float*)d_out;

    // ws layout (MB offsets):
    //   xb   bf16 256x4096   2 MB @ 0
    //   w2t  bf16 256x1024  .5 MB @ 2
    //   H    bf16 16384x256  8 MB @ 3
    //   Y    bf16 1024x256  .5 MB @ 11
    //   xb2  fp32 256        1 KB @ 12
    char* ws = (char*)d_ws;
    __bf16* xb  = (__bf16*)(ws);
    __bf16* w2t = (__bf16*)(ws + (2u << 20));
    __bf16* H   = (__bf16*)(ws + (3u << 20));
    __bf16* Y   = (__bf16*)(ws + (11u << 20));
    float*  xb2 = (float*)(ws + (12u << 20));

    // K1: all prep (hidden-MFMA + x-cvt/rowdot + w2 transpose)
    prep_kernel<<<1536, 256, 0, stream>>>(codebook, w1, b1, x, b2, w2,
                                          H, xb, xb2, w2t);

    // K2: Y = xr(1024x1024) @ w2t^T -> bf16   (M=1024, N=256, K=1024)
    {
        dim3 grid(HIDDEN / 64, 1024 / 64, 1);    // 4 x 16 = 64 blocks
        gemm_bt64<128, 0><<<grid, 256, 0, stream>>>(
            xb, w2t, nullptr, nullptr, Y, 1024, HIDDEN, 1024);
    }

    // K3: out = Ycat(256x1024) @ Hflat^T + bias[col] + xb2[row]
    {
        dim3 grid(OUT_F / 64, TOKENS / 64, 1);   // 64 x 4 = 256 blocks
        gemm_bt64<128, 1><<<grid, 256, 0, stream>>>(
            Y, H, bias, xb2, out, TOKENS, OUT_F, 1024);
    }
}